// Round 1
// baseline (1261.301 us; speedup 1.0000x reference)
//
#include <hip/hip_runtime.h>

#define B_ 16
#define T_ 64
#define C_ 4
#define H_ 129
#define W_ 2
#define HID_ 32
#define R_ 9
#define NCHUNK_ 15                    // ceil(129/9)
#define SB_ (B_*HID_*H_*W_)           // 132096 floats per state buffer

__device__ __forceinline__ float sigf(float x)   { return 1.0f / (1.0f + __expf(-x)); }
__device__ __forceinline__ float tanhf_(float x) { return 1.0f - 2.0f / (1.0f + __expf(2.0f * x)); }

// Pre-transpose conv weights to [ic][kh][oc] (coalesced per-wave weight loads)
// and fc1_w to [j][o] (coalesced head GEMV).
__global__ __launch_bounds__(256) void init_kernel(
    const float* __restrict__ w0, const float* __restrict__ w1,
    const float* __restrict__ fc1w,
    float* __restrict__ W0T, float* __restrict__ W1T, float* __restrict__ FC1T)
{
  int i = blockIdx.x * 256 + threadIdx.x;
  if (i < 36 * 3 * 128) {
    int ic = i / (3 * 128), kh = (i / 128) % 3, oc = i % 128;
    W0T[i] = w0[(oc * 36 + ic) * 3 + kh];
  }
  int j = i - 36 * 3 * 128;
  if (j >= 0 && j < 64 * 3 * 128) {
    int ic = j / (3 * 128), kh = (j / 128) % 3, oc = j % 128;
    W1T[j] = w1[(oc * 64 + ic) * 3 + kh];
  }
  int k = i - 36 * 3 * 128 - 64 * 3 * 128;
  if (k >= 0 && k < 258 * 256) {
    int jj = k / 256, o = k % 256;
    FC1T[k] = fc1w[o * 258 + jj];
  }
}

// One fused ConvLSTM time step (both layers). Grid: B_*NCHUNK_ blocks.
// Block owns rows [own0, own1) of one sample; computes a 1-row redundant halo
// of layer-0 output so layer-1 needs no cross-block data within the step.
__global__ __launch_bounds__(256) void step_kernel(
    const float* __restrict__ x, const int* __restrict__ lens,
    const float* __restrict__ W0T, const float* __restrict__ b0,
    const float* __restrict__ W1T, const float* __restrict__ b1,
    const float* __restrict__ h0i, float* __restrict__ h0o,
    const float* __restrict__ c0i, float* __restrict__ c0o,
    const float* __restrict__ h1i, float* __restrict__ h1o,
    float* __restrict__ c1, float* __restrict__ hlast, int t)
{
  __shared__ float in0[36][2][16];   // concat(x_t, h0) rows own0-2 .. own0+10
  __shared__ float in1[64][2][16];   // concat(h0_new, h1) rows own0-1 .. own0+9
  __shared__ float zt[128][2][13];   // conv output exchange tile (pad 13: 2-way banks)

  const int tid   = threadIdx.x;
  const int blk   = blockIdx.x;
  const int b     = blk / NCHUNK_;
  const int chunk = blk % NCHUNK_;
  const int own0  = chunk * R_;
  const int own1  = min(own0 + R_, H_);
  const int zhi   = min(own1 + 1, H_);  // exclusive end of valid layer0 z rows

  // ---- stage: in0 (x + h0, 13 rows, zero-padded), in1 (zero h0half + h1, 11 rows)
  for (int l = tid; l < 36 * 26; l += 256) {
    int ic = l / 26, rem = l % 26, tr = rem >> 1, cc = rem & 1;
    int gr = own0 - 2 + tr;
    float v = 0.f;
    if (gr >= 0 && gr < H_) {
      v = (ic < C_) ? x[((b * T_ + t) * C_ + ic) * H_ * W_ + gr * W_ + cc]
                    : h0i[((b * HID_ + (ic - C_)) * H_ + gr) * W_ + cc];
    }
    in0[ic][cc][tr] = v;
  }
  for (int l = tid; l < 64 * 22; l += 256) {
    int ic = l / 22, rem = l % 22, tr = rem >> 1, cc = rem & 1;
    int gr = own0 - 1 + tr;
    float v = 0.f;
    if (ic >= HID_ && gr >= 0 && gr < H_)
      v = h1i[((b * HID_ + (ic - HID_)) * H_ + gr) * W_ + cc];
    in1[ic][cc][tr] = v;
  }
  __syncthreads();

  const int oc = tid & 127;
  const int cc = tid >> 7;

  // ---- conv0: z rows r=0..10 <-> global own0-1+r (edge rows garbage, guarded later)
  {
    float acc[11];
    float bv = b0[oc];
    #pragma unroll
    for (int r = 0; r < 11; ++r) acc[r] = bv;
    for (int ic = 0; ic < 36; ++ic) {
      float inv[16];
      const float4* p = (const float4*)&in0[ic][cc][0];
      *(float4*)&inv[0]  = p[0];
      *(float4*)&inv[4]  = p[1];
      *(float4*)&inv[8]  = p[2];
      *(float4*)&inv[12] = p[3];
      const float* wp = W0T + ic * 3 * 128 + oc;
      #pragma unroll
      for (int kh = 0; kh < 3; ++kh) {
        float w = wp[kh * 128];
        #pragma unroll
        for (int r = 0; r < 11; ++r) acc[r] = fmaf(w, inv[r + kh], acc[r]);
      }
    }
    #pragma unroll
    for (int r = 0; r < 11; ++r) zt[oc][cc][r] = acc[r];
  }
  __syncthreads();

  // ---- gate0: update c0/h0 on rows own0-1 .. zhi-1 (halo kept in LDS only)
  for (int it = tid; it < 32 * 22; it += 256) {
    int hid = it / 22, rem = it % 22, r = rem >> 1, c2 = rem & 1;
    int zr = own0 - 1 + r;
    if (zr >= 0 && zr < zhi) {
      float zi = zt[hid][c2][r], zf = zt[hid + 32][c2][r];
      float zo = zt[hid + 64][c2][r], zg = zt[hid + 96][c2][r];
      int cidx = ((b * HID_ + hid) * H_ + zr) * W_ + c2;
      float cp = c0i[cidx];
      float cn = sigf(zf) * cp + sigf(zi) * tanhf_(zg);
      float hn = sigf(zo) * tanhf_(cn);
      in1[hid][c2][r] = hn;                       // layer1 input (incl. halo)
      if (zr >= own0 && zr < own1) { c0o[cidx] = cn; h0o[cidx] = hn; }
    }
  }
  __syncthreads();

  // ---- conv1: z rows r=0..8 <-> global own0+r
  {
    float acc[9];
    float bv = b1[oc];
    #pragma unroll
    for (int r = 0; r < 9; ++r) acc[r] = bv;
    for (int ic = 0; ic < 64; ++ic) {
      float inv[12];
      const float4* p = (const float4*)&in1[ic][cc][0];
      *(float4*)&inv[0] = p[0];
      *(float4*)&inv[4] = p[1];
      *(float4*)&inv[8] = p[2];
      const float* wp = W1T + ic * 3 * 128 + oc;
      #pragma unroll
      for (int kh = 0; kh < 3; ++kh) {
        float w = wp[kh * 128];
        #pragma unroll
        for (int r = 0; r < 9; ++r) acc[r] = fmaf(w, inv[r + kh], acc[r]);
      }
    }
    #pragma unroll
    for (int r = 0; r < 9; ++r) zt[oc][cc][r] = acc[r];
  }
  __syncthreads();

  // ---- gate1: update c1/h1 on owned rows; capture h_last at t == len-1
  {
    int len = lens[b];
    int nz1 = own1 - own0;
    for (int it = tid; it < 32 * 18; it += 256) {
      int hid = it / 18, rem = it % 18, r = rem >> 1, c2 = rem & 1;
      if (r < nz1) {
        int zr = own0 + r;
        float zi = zt[hid][c2][r], zf = zt[hid + 32][c2][r];
        float zo = zt[hid + 64][c2][r], zg = zt[hid + 96][c2][r];
        int cidx = ((b * HID_ + hid) * H_ + zr) * W_ + c2;
        float cp = c1[cidx];
        float cn = sigf(zf) * cp + sigf(zi) * tanhf_(zg);
        float hn = sigf(zo) * tanhf_(cn);
        c1[cidx] = cn;
        h1o[cidx] = hn;
        if (t == len - 1)
          hlast[(b * HID_ + hid) * H_ * W_ + zr * W_ + c2] = hn;
      }
    }
  }
}

// nin (1x1 conv over HID) -> fc1 -> fc2. One block per sample.
__global__ __launch_bounds__(256) void head_kernel(
    const float* __restrict__ hlast,
    const float* __restrict__ ninw, const float* __restrict__ ninb,
    const float* __restrict__ FC1T, const float* __restrict__ fc1b,
    const float* __restrict__ fc2w, const float* __restrict__ fc2b,
    float* __restrict__ out)
{
  __shared__ float lin[258];
  __shared__ float o1[256];
  int b = blockIdx.x, tid = threadIdx.x;
  for (int j = tid; j < 258; j += 256) {
    float s = ninb[0];
    #pragma unroll
    for (int h = 0; h < 32; ++h) s = fmaf(ninw[h], hlast[(b * 32 + h) * 258 + j], s);
    lin[j] = s;
  }
  __syncthreads();
  {
    float a = fc1b[tid];
    for (int j = 0; j < 258; ++j) a = fmaf(lin[j], FC1T[j * 256 + tid], a);
    o1[tid] = a;
  }
  __syncthreads();
  if (tid < 2) {
    float s = fc2b[tid];
    for (int k2 = 0; k2 < 256; ++k2) s = fmaf(o1[k2], fc2w[tid * 256 + k2], s);
    out[b * 2 + tid] = s;
  }
}

extern "C" void kernel_launch(void* const* d_in, const int* in_sizes, int n_in,
                              void* d_out, int out_size, void* d_ws, size_t ws_size,
                              hipStream_t stream) {
  const float* x     = (const float*)d_in[0];
  const int*   lens  = (const int*)  d_in[1];
  const float* w0    = (const float*)d_in[2];
  const float* b0    = (const float*)d_in[3];
  const float* w1    = (const float*)d_in[4];
  const float* b1    = (const float*)d_in[5];
  const float* ninw  = (const float*)d_in[6];
  const float* ninb  = (const float*)d_in[7];
  const float* fc1w  = (const float*)d_in[8];
  const float* fc1b  = (const float*)d_in[9];
  const float* fc2w  = (const float*)d_in[10];
  const float* fc2b  = (const float*)d_in[11];
  float* out = (float*)d_out;
  float* ws  = (float*)d_ws;

  const size_t SB = (size_t)SB_;
  float* h0A   = ws;             // |-- zeroed region (4*SB): t=0 "ping" state
  float* c0A   = h0A + SB;
  float* h1A   = c0A + SB;
  float* c1    = h1A + SB;       // single-buffered (owned rows only)
  float* h0B   = c1 + SB;
  float* c0B   = h0B + SB;
  float* h1B   = c0B + SB;
  float* hlast = h1B + SB;
  float* W0T   = hlast + SB;     // 36*3*128
  float* W1T   = W0T + 36 * 3 * 128;   // 64*3*128
  float* FC1T  = W1T + 64 * 3 * 128;   // 258*256

  hipMemsetAsync(ws, 0, 4 * SB * sizeof(float), stream);
  init_kernel<<<408, 256, 0, stream>>>(w0, w1, fc1w, W0T, W1T, FC1T);

  for (int t = 0; t < T_; ++t) {
    const float *h0in, *c0in, *h1in;
    float *h0out, *c0out, *h1out;
    if ((t & 1) == 0) { h0in = h0A; c0in = c0A; h1in = h1A; h0out = h0B; c0out = c0B; h1out = h1B; }
    else              { h0in = h0B; c0in = c0B; h1in = h1B; h0out = h0A; c0out = c0A; h1out = h1A; }
    step_kernel<<<B_ * NCHUNK_, 256, 0, stream>>>(
        x, lens, W0T, b0, W1T, b1,
        h0in, h0out, c0in, c0out, h1in, h1out, c1, hlast, t);
  }

  head_kernel<<<B_, 256, 0, stream>>>(hlast, ninw, ninb, FC1T, fc1b, fc2w, fc2b, out);
}